// Round 8
// baseline (166.041 us; speedup 1.0000x reference)
//
#include <hip/hip_runtime.h>
#include <stdint.h>

// MHABlock: b=8, c=128, heads=8, d=16, spatial 32x32 (p=1024).
// R8: MEASUREMENT ROUND. Kernels identical to R7 (passed, absmax 0.125).
// Launch sequence replays (zero, attn) 4x to differentially measure
// attn+zero time vs the per-iteration harness floor (fills/restores/gaps).
// Output is bit-identical (each pair re-zeros then fully re-accumulates).

typedef __bf16 bf16x8 __attribute__((ext_vector_type(8)));
typedef float f32x16 __attribute__((ext_vector_type(16)));

// ws layout (units: shorts): Q | K | V, 1M shorts each
#define QOFF  0u
#define KOFF  (1u << 20)
#define VOFF  (2u << 20)

static __device__ __forceinline__ unsigned short f2bf(float f) {
  union { float f; uint32_t u; } v; v.f = f;
  uint32_t r = (v.u + 0x7FFFu + ((v.u >> 16) & 1u)) >> 16;  // RNE
  return (unsigned short)r;
}
static __device__ __forceinline__ uint32_t pkrne(float lo, float hi) {
  return (uint32_t)f2bf(lo) | ((uint32_t)f2bf(hi) << 16);
}
static __device__ __forceinline__ uint32_t pktrunc(float lo, float hi) {
  return (__builtin_bit_cast(uint32_t, hi) & 0xffff0000u) |
         (__builtin_bit_cast(uint32_t, lo) >> 16);
}
static __device__ __forceinline__ float fexp2(float x) {
  float r;
  asm("v_exp_f32 %0, %1" : "=v"(r) : "v"(x));  // non-volatile: schedulable
  return r;
}
static __device__ __forceinline__ f32x16 zero16() {
  f32x16 z;
#pragma unroll
  for (int i = 0; i < 16; ++i) z[i] = 0.f;
  return z;
}
// swap bits 2,3 (V spatial permutation within each 32-block)
static __device__ __forceinline__ int perm23(int p) {
  return (p & ~12) | ((p & 4) << 1) | ((p & 8) >> 1);
}
static __device__ __forceinline__ bf16x8 pack8(float f0, float f1, float f2,
                                               float f3, float f4, float f5,
                                               float f6, float f7) {
  uint4 u = make_uint4(pkrne(f0, f1), pkrne(f2, f3), pkrne(f4, f5), pkrne(f6, f7));
  return __builtin_bit_cast(bf16x8, u);
}

// ---------------------------------------------------------------------------
__global__ __launch_bounds__(256) void zero_kernel(float4* __restrict__ out) {
  out[(size_t)blockIdx.x * 256 + threadIdx.x] = make_float4(0.f, 0.f, 0.f, 0.f);
}

// ---------------------------------------------------------------------------
// proj (MFMA, fused fp32->bf16): D[out 32][p 32], K=128.
// grid = b*48 + mat*16 + ptile (384), block = 256.
// ---------------------------------------------------------------------------
__global__ __launch_bounds__(256) void proj_kernel(
    const float* __restrict__ x, const float* __restrict__ wq,
    const float* __restrict__ wk, const float* __restrict__ wv,
    unsigned short* __restrict__ ws) {
  int bid = blockIdx.x;
  int ptile = bid & 15;
  int mat = (bid >> 4) % 3;
  int b = bid / 48;
  int t = threadIdx.x;
  int wave = t >> 6, lane = t & 63;
  int h = lane >> 5, c = lane & 31;
  int out0 = wave * 32;

  const float* w = (mat == 0) ? wq : ((mat == 1) ? wk : wv);
  const float* wrow = w + (size_t)(out0 + c) * 128 + h * 8;      // A: W[out0+c][k]
  const float* xcol = x + (size_t)b * 131072 + ptile * 64 + c;   // B: x[ch][p]

  f32x16 acc0 = zero16(), acc1 = zero16();
#pragma unroll
  for (int kt = 0; kt < 8; ++kt) {
    int ch0 = kt * 16 + h * 8;
    float4 wa = *(const float4*)(wrow + kt * 16);
    float4 wb4 = *(const float4*)(wrow + kt * 16 + 4);
    float xb0[8], xb1[8];
#pragma unroll
    for (int j = 0; j < 8; ++j) {
      xb0[j] = xcol[(size_t)(ch0 + j) * 1024];
      xb1[j] = xcol[(size_t)(ch0 + j) * 1024 + 32];
    }
    bf16x8 af = pack8(wa.x, wa.y, wa.z, wa.w, wb4.x, wb4.y, wb4.z, wb4.w);
    bf16x8 b0 = pack8(xb0[0], xb0[1], xb0[2], xb0[3], xb0[4], xb0[5], xb0[6], xb0[7]);
    bf16x8 b1 = pack8(xb1[0], xb1[1], xb1[2], xb1[3], xb1[4], xb1[5], xb1[6], xb1[7]);
    acc0 = __builtin_amdgcn_mfma_f32_32x32x16_bf16(af, b0, acc0, 0, 0, 0);
    acc1 = __builtin_amdgcn_mfma_f32_32x32x16_bf16(af, b1, acc1, 0, 0, 0);
  }

  if (mat < 2) {
    // Q: fold softmax scale d^-0.5 * log2(e) (attn uses exp2)
    float s = (mat == 0) ? 0.36067376022224085f : 1.0f;
    unsigned short* dst = ws + ((mat == 0) ? QOFF : KOFF);
#pragma unroll
    for (int nt = 0; nt < 2; ++nt) {
      f32x16 a = nt ? acc1 : acc0;
      int p = ptile * 64 + nt * 32 + c;
#pragma unroll
      for (int rg = 0; rg < 4; ++rg) {
        int bn = b * 8 + wave * 2 + (rg >> 1);
        int dbase = ((rg & 1) ? 8 : 0) + 4 * h;
        uint32_t lo = pkrne(a[rg * 4 + 0] * s, a[rg * 4 + 1] * s);
        uint32_t hi = pkrne(a[rg * 4 + 2] * s, a[rg * 4 + 3] * s);
        *(uint2*)(dst + (size_t)bn * 16384 + (size_t)p * 16 + dbase) =
            make_uint2(lo, hi);
      }
    }
  } else {
#pragma unroll
    for (int nt = 0; nt < 2; ++nt) {
      f32x16 a = nt ? acc1 : acc0;
      int p = ptile * 64 + nt * 32 + c;
      int pp = perm23(p);
#pragma unroll
      for (int r = 0; r < 16; ++r) {
        int moff = (r & 3) + 8 * (r >> 2) + 4 * h;
        int head = (out0 + moff) >> 4;
        int d = moff & 15;
        ws[VOFF + (size_t)(b * 8 + head) * 16384 + (size_t)d * 1024 + pp] =
            f2bf(a[r]);
      }
    }
  }
}

// ---------------------------------------------------------------------------
// attn: grid = (bn*8+qc)*2+xh (1024 blocks), block = 256 (4 waves),
// 32 q/wave, 16 x-blocks per block. No LDS, no barriers. Partials
// atomicAdd'd into zeroed out (exactly 2 contributors per address).
// ---------------------------------------------------------------------------
__global__ __launch_bounds__(256) void attn_kernel(
    const unsigned short* __restrict__ ws, float* __restrict__ out) {
  int bid = blockIdx.x;
  int xh = bid & 1;
  int qc = (bid >> 1) & 7;
  int bn = bid >> 4;
  const unsigned short* Qg = ws + QOFF + (size_t)bn * 16384;
  const unsigned short* Kg = ws + KOFF + (size_t)bn * 16384;
  const unsigned short* Vg = ws + VOFF + (size_t)bn * 16384;

  int t = threadIdx.x;
  int wave = t >> 6, lane = t & 63;
  int h = lane >> 5, c = lane & 31;
  int q0 = qc * 128 + wave * 32;
  int x0 = xh * 16;

  // Q B-frag: B[k=d=8h+j][n=q=c], K=16 exact
  bf16x8 qb = __builtin_bit_cast(
      bf16x8, *(const uint4*)(Qg + (size_t)(q0 + c) * 16 + h * 8));

  // K A-frag: lane reads K[x*32 + c][8h..8h+7]  (coalesced 16B/lane)
  const unsigned short* kbase = Kg + (size_t)c * 16 + h * 8;
  // V A-frag: lane reads V'[c&15][x*32 + 8h..]
  const unsigned short* vbase = Vg + (size_t)(c & 15) * 1024 + h * 8;

  f32x16 accA = zero16(), accB = zero16();
  uint4 kf  = *(const uint4*)(kbase + (size_t)x0 * 512);
  uint4 v0f = *(const uint4*)(vbase + x0 * 32);
  uint4 v1f = *(const uint4*)(vbase + x0 * 32 + 16);

#pragma unroll 2
  for (int xi = 0; xi < 16; ++xi) {
    int x = x0 + xi;
    bf16x8 ka  = __builtin_bit_cast(bf16x8, kf);
    bf16x8 va0 = __builtin_bit_cast(bf16x8, v0f);
    bf16x8 va1 = __builtin_bit_cast(bf16x8, v1f);
    if (xi < 15) {  // prefetch next x-block
      kf  = *(const uint4*)(kbase + (size_t)(x + 1) * 512);
      v0f = *(const uint4*)(vbase + (x + 1) * 32);
      v1f = *(const uint4*)(vbase + (x + 1) * 32 + 16);
    }

    // S^T[slot=(r&3)+8(r>>2)+4h][q=c], slot = natural y within block
    f32x16 sv = __builtin_amdgcn_mfma_f32_32x32x16_bf16(ka, qb, zero16(), 0, 0, 0);

    float e[16];
#pragma unroll
    for (int r = 0; r < 16; ++r) e[r] = fexp2(sv[r]);
    float s0 = (e[0] + e[1]) + (e[2] + e[3]);
    float s1 = (e[4] + e[5]) + (e[6] + e[7]);
    float s2 = (e[8] + e[9]) + (e[10] + e[11]);
    float s3 = (e[12] + e[13]) + (e[14] + e[15]);
    float sum = (s0 + s1) + (s2 + s3);
    sum += __shfl_xor(sum, 32);
    float rs = __builtin_amdgcn_rcpf(sum);

    uint32_t pk[8];
#pragma unroll
    for (int j = 0; j < 8; ++j)
      pk[j] = pktrunc(e[2 * j] * rs, e[2 * j + 1] * rs);
    bf16x8 p0 = __builtin_bit_cast(bf16x8, make_uint4(pk[0], pk[1], pk[2], pk[3]));
    bf16x8 p1 = __builtin_bit_cast(bf16x8, make_uint4(pk[4], pk[5], pk[6], pk[7]));

    // O^T[d][q] += V'·P ; two independent accumulators
    accA = __builtin_amdgcn_mfma_f32_32x32x16_bf16(va0, p0, accA, 0, 0, 0);
    accB = __builtin_amdgcn_mfma_f32_32x32x16_bf16(va1, p1, accB, 0, 0, 0);
  }

  // Epilogue: D rows 0..15 valid; combine x-halves via atomic f32 add
#pragma unroll
  for (int r = 0; r < 8; ++r) {
    int d = (r & 3) + 8 * (r >> 2) + 4 * h;
    atomicAdd(out + (size_t)(bn * 16 + d) * 1024 + q0 + c, accA[r] + accB[r]);
  }
}

// ---------------------------------------------------------------------------
extern "C" void kernel_launch(void* const* d_in, const int* in_sizes, int n_in,
                              void* d_out, int out_size, void* d_ws, size_t ws_size,
                              hipStream_t stream) {
  const float* x  = (const float*)d_in[0];
  const float* wq = (const float*)d_in[1];
  const float* wk = (const float*)d_in[2];
  const float* wv = (const float*)d_in[3];
  unsigned short* ws = (unsigned short*)d_ws;
  float* out = (float*)d_out;

  proj_kernel<<<dim3(384), dim3(256), 0, stream>>>(x, wq, wk, wv, ws);
  // Differential measurement: replay (zero, attn) 4x. Each pair re-zeros out
  // and fully re-accumulates -> final output identical; added time = 3x pair.
#pragma unroll
  for (int rep = 0; rep < 4; ++rep) {
    zero_kernel<<<dim3(1024), dim3(256), 0, stream>>>((float4*)out);
    attn_kernel<<<dim3(1024), dim3(256), 0, stream>>>(ws, out);
  }
}

// Round 9
// 93.371 us; speedup vs baseline: 1.7783x; 1.7783x over previous
//
#include <hip/hip_runtime.h>
#include <stdint.h>

// MHABlock: b=8, c=128, heads=8, d=16, spatial 32x32 (p=1024).
// Softmax over last spatial axis only -> independent 32-key blocks.
// R9: proven R5/R7 math core; softmax sum-tree and rs-scaling as float2
// vector ops (v_pk_*; clang-guaranteed semantics), 512 blocks, direct
// stores (no zero kernel / atomics). Differential R8 measurement: floor
// ~67us, attn ~21us (VALU-issue incl. quarter-rate exp), proj ~4us.
// S^T = K*Q^T via mfma_32x32x16 (K-dim=16 exact); V stored y-bits-2,3-
// swapped so PV B-frags are the sequential in-lane pack of exp'd scores.

typedef __bf16 bf16x8 __attribute__((ext_vector_type(8)));
typedef float f32x16 __attribute__((ext_vector_type(16)));
typedef float f32x2 __attribute__((ext_vector_type(2)));

// ws layout (units: shorts): Q | K | V, 1M shorts each
#define QOFF  0u
#define KOFF  (1u << 20)
#define VOFF  (2u << 20)

static __device__ __forceinline__ unsigned short f2bf(float f) {
  union { float f; uint32_t u; } v; v.f = f;
  uint32_t r = (v.u + 0x7FFFu + ((v.u >> 16) & 1u)) >> 16;  // RNE
  return (unsigned short)r;
}
static __device__ __forceinline__ uint32_t pkrne(float lo, float hi) {
  return (uint32_t)f2bf(lo) | ((uint32_t)f2bf(hi) << 16);
}
static __device__ __forceinline__ uint32_t pktrunc(float lo, float hi) {
  return (__builtin_bit_cast(uint32_t, hi) & 0xffff0000u) |
         (__builtin_bit_cast(uint32_t, lo) >> 16);
}
static __device__ __forceinline__ float fexp2(float x) {
  float r;
  asm("v_exp_f32 %0, %1" : "=v"(r) : "v"(x));  // non-volatile: schedulable
  return r;
}
static __device__ __forceinline__ f32x16 zero16() {
  f32x16 z;
#pragma unroll
  for (int i = 0; i < 16; ++i) z[i] = 0.f;
  return z;
}
// swap bits 2,3 (V spatial permutation within each 32-block)
static __device__ __forceinline__ int perm23(int p) {
  return (p & ~12) | ((p & 4) << 1) | ((p & 8) >> 1);
}
static __device__ __forceinline__ bf16x8 pack8(float f0, float f1, float f2,
                                               float f3, float f4, float f5,
                                               float f6, float f7) {
  uint4 u = make_uint4(pkrne(f0, f1), pkrne(f2, f3), pkrne(f4, f5), pkrne(f6, f7));
  return __builtin_bit_cast(bf16x8, u);
}

// ---------------------------------------------------------------------------
// proj (MFMA, fused fp32->bf16): D[out 32][p 32], K=128.
// grid = b*48 + mat*16 + ptile (384), block = 256 (4 waves; wave = 32-out
// m-tile, 2 n-tiles of 32 p). Q/K stored [bn][p][d] (Q scaled by
// 0.25*log2e); V stored [bn][d][perm23(p)].
// ---------------------------------------------------------------------------
__global__ __launch_bounds__(256) void proj_kernel(
    const float* __restrict__ x, const float* __restrict__ wq,
    const float* __restrict__ wk, const float* __restrict__ wv,
    unsigned short* __restrict__ ws) {
  int bid = blockIdx.x;
  int ptile = bid & 15;
  int mat = (bid >> 4) % 3;
  int b = bid / 48;
  int t = threadIdx.x;
  int wave = t >> 6, lane = t & 63;
  int h = lane >> 5, c = lane & 31;
  int out0 = wave * 32;

  const float* w = (mat == 0) ? wq : ((mat == 1) ? wk : wv);
  const float* wrow = w + (size_t)(out0 + c) * 128 + h * 8;      // A: W[out0+c][k]
  const float* xcol = x + (size_t)b * 131072 + ptile * 64 + c;   // B: x[ch][p]

  f32x16 acc0 = zero16(), acc1 = zero16();
#pragma unroll
  for (int kt = 0; kt < 8; ++kt) {
    int ch0 = kt * 16 + h * 8;
    float4 wa = *(const float4*)(wrow + kt * 16);
    float4 wb4 = *(const float4*)(wrow + kt * 16 + 4);
    float xb0[8], xb1[8];
#pragma unroll
    for (int j = 0; j < 8; ++j) {
      xb0[j] = xcol[(size_t)(ch0 + j) * 1024];
      xb1[j] = xcol[(size_t)(ch0 + j) * 1024 + 32];
    }
    bf16x8 af = pack8(wa.x, wa.y, wa.z, wa.w, wb4.x, wb4.y, wb4.z, wb4.w);
    bf16x8 b0 = pack8(xb0[0], xb0[1], xb0[2], xb0[3], xb0[4], xb0[5], xb0[6], xb0[7]);
    bf16x8 b1 = pack8(xb1[0], xb1[1], xb1[2], xb1[3], xb1[4], xb1[5], xb1[6], xb1[7]);
    acc0 = __builtin_amdgcn_mfma_f32_32x32x16_bf16(af, b0, acc0, 0, 0, 0);
    acc1 = __builtin_amdgcn_mfma_f32_32x32x16_bf16(af, b1, acc1, 0, 0, 0);
  }

  if (mat < 2) {
    // Q: fold softmax scale d^-0.5 * log2(e) (attn uses exp2)
    float s = (mat == 0) ? 0.36067376022224085f : 1.0f;
    unsigned short* dst = ws + ((mat == 0) ? QOFF : KOFF);
#pragma unroll
    for (int nt = 0; nt < 2; ++nt) {
      f32x16 a = nt ? acc1 : acc0;
      int p = ptile * 64 + nt * 32 + c;
#pragma unroll
      for (int rg = 0; rg < 4; ++rg) {
        int bn = b * 8 + wave * 2 + (rg >> 1);
        int dbase = ((rg & 1) ? 8 : 0) + 4 * h;
        uint32_t lo = pkrne(a[rg * 4 + 0] * s, a[rg * 4 + 1] * s);
        uint32_t hi = pkrne(a[rg * 4 + 2] * s, a[rg * 4 + 3] * s);
        *(uint2*)(dst + (size_t)bn * 16384 + (size_t)p * 16 + dbase) =
            make_uint2(lo, hi);
      }
    }
  } else {
#pragma unroll
    for (int nt = 0; nt < 2; ++nt) {
      f32x16 a = nt ? acc1 : acc0;
      int p = ptile * 64 + nt * 32 + c;
      int pp = perm23(p);
#pragma unroll
      for (int r = 0; r < 16; ++r) {
        int moff = (r & 3) + 8 * (r >> 2) + 4 * h;
        int head = (out0 + moff) >> 4;
        int d = moff & 15;
        ws[VOFF + (size_t)(b * 8 + head) * 16384 + (size_t)d * 1024 + pp] =
            f2bf(a[r]);
      }
    }
  }
}

// ---------------------------------------------------------------------------
// attn: grid = bn*8+qc (512), block = 256 (4 waves), 32 q/wave, 32 x-blocks.
// No LDS, no barriers, direct stores. Per x-block: S^T = mfma32(K, Q^T) ->
// 16 exp2 -> packed-f32 sum tree + 1 shfl -> pktrunc pack -> two
// independent PV MFMAs. K/V frags loaded from global with next-iter prefetch.
// ---------------------------------------------------------------------------
__global__ __launch_bounds__(256) void attn_kernel(
    const unsigned short* __restrict__ ws, float* __restrict__ out) {
  int bid = blockIdx.x;
  int qc = bid & 7, bn = bid >> 3;
  const unsigned short* Qg = ws + QOFF + (size_t)bn * 16384;
  const unsigned short* Kg = ws + KOFF + (size_t)bn * 16384;
  const unsigned short* Vg = ws + VOFF + (size_t)bn * 16384;

  int t = threadIdx.x;
  int wave = t >> 6, lane = t & 63;
  int h = lane >> 5, c = lane & 31;
  int q0 = qc * 128 + wave * 32;

  // Q B-frag: B[k=d=8h+j][n=q=c], K=16 exact
  bf16x8 qb = __builtin_bit_cast(
      bf16x8, *(const uint4*)(Qg + (size_t)(q0 + c) * 16 + h * 8));

  // K A-frag: lane reads K[x*32 + c][8h..8h+7]  (coalesced 16B/lane)
  const unsigned short* kbase = Kg + (size_t)c * 16 + h * 8;
  // V A-frag: lane reads V'[c&15][x*32 + 8h..]
  const unsigned short* vbase = Vg + (size_t)(c & 15) * 1024 + h * 8;

  f32x16 accA = zero16(), accB = zero16();
  uint4 kf  = *(const uint4*)(kbase);
  uint4 v0f = *(const uint4*)(vbase);
  uint4 v1f = *(const uint4*)(vbase + 16);

#pragma unroll 2
  for (int x = 0; x < 32; ++x) {
    bf16x8 ka  = __builtin_bit_cast(bf16x8, kf);
    bf16x8 va0 = __builtin_bit_cast(bf16x8, v0f);
    bf16x8 va1 = __builtin_bit_cast(bf16x8, v1f);
    if (x < 31) {  // prefetch next x-block
      kf  = *(const uint4*)(kbase + (size_t)(x + 1) * 512);
      v0f = *(const uint4*)(vbase + (x + 1) * 32);
      v1f = *(const uint4*)(vbase + (x + 1) * 32 + 16);
    }

    // S^T[slot=(r&3)+8(r>>2)+4h][q=c], slot = natural y within block
    f32x16 sv = __builtin_amdgcn_mfma_f32_32x32x16_bf16(ka, qb, zero16(), 0, 0, 0);

    // 16 exp2 (quarter-rate VALU; independent -> schedulable)
    f32x2 e2[8];
#pragma unroll
    for (int j = 0; j < 8; ++j) {
      e2[j].x = fexp2(sv[2 * j]);
      e2[j].y = fexp2(sv[2 * j + 1]);
    }
    // packed sum tree: 7 v_pk_add_f32 equivalents
    f32x2 t0 = (e2[0] + e2[1]) + (e2[2] + e2[3]);
    f32x2 t1 = (e2[4] + e2[5]) + (e2[6] + e2[7]);
    f32x2 ts = t0 + t1;
    float sum = ts.x + ts.y;
    sum += __shfl_xor(sum, 32);
    float rs = __builtin_amdgcn_rcpf(sum);
    f32x2 rr; rr.x = rs; rr.y = rs;

    uint32_t pk[8];
#pragma unroll
    for (int j = 0; j < 8; ++j) {
      f32x2 m = e2[j] * rr;  // packed mul
      pk[j] = pktrunc(m.x, m.y);
    }
    bf16x8 p0 = __builtin_bit_cast(bf16x8, make_uint4(pk[0], pk[1], pk[2], pk[3]));
    bf16x8 p1 = __builtin_bit_cast(bf16x8, make_uint4(pk[4], pk[5], pk[6], pk[7]));

    // O^T[d][q] += V'·P ; two independent accumulators
    accA = __builtin_amdgcn_mfma_f32_32x32x16_bf16(va0, p0, accA, 0, 0, 0);
    accB = __builtin_amdgcn_mfma_f32_32x32x16_bf16(va1, p1, accB, 0, 0, 0);
  }

  // Epilogue: D rows 0..15 valid (rows 16..31 are duplicate-V garbage)
#pragma unroll
  for (int r = 0; r < 8; ++r) {
    int d = (r & 3) + 8 * (r >> 2) + 4 * h;
    out[(size_t)(bn * 16 + d) * 1024 + q0 + c] = accA[r] + accB[r];
  }
}

// ---------------------------------------------------------------------------
extern "C" void kernel_launch(void* const* d_in, const int* in_sizes, int n_in,
                              void* d_out, int out_size, void* d_ws, size_t ws_size,
                              hipStream_t stream) {
  const float* x  = (const float*)d_in[0];
  const float* wq = (const float*)d_in[1];
  const float* wk = (const float*)d_in[2];
  const float* wv = (const float*)d_in[3];
  unsigned short* ws = (unsigned short*)d_ws;
  float* out = (float*)d_out;

  proj_kernel<<<dim3(384), dim3(256), 0, stream>>>(x, wq, wk, wv, ws);
  attn_kernel<<<dim3(512), dim3(256), 0, stream>>>(ws, out);
}

// Round 11
// 91.675 us; speedup vs baseline: 1.8112x; 1.0185x over previous
//
#include <hip/hip_runtime.h>
#include <stdint.h>

// MHABlock: b=8, c=128, heads=8, d=16, spatial 32x32 (p=1024).
// Softmax over last spatial axis only -> independent 32-key blocks.
// R11: deferred-normalization attn. PV runs on UNNORMALIZED exp2 scores into
// a fresh per-x tile (C=0); per-query 1/sum folded in afterwards with 8
// scalar fmacs (all D-regs of a lane share q=c). The sum tree + shfl + rcp
// thus run in parallel with pack+PV instead of on the critical path.
// Everything else identical to R9 (passed, 93.4us, absmax 0.125).
// S^T = K*Q^T via mfma_32x32x16 (K=16 exact); V stored y-bits-2,3-swapped so
// PV B-frags are sequential in-lane packs of the exp'd scores.

typedef __bf16 bf16x8 __attribute__((ext_vector_type(8)));
typedef float f32x16 __attribute__((ext_vector_type(16)));
typedef float f32x2 __attribute__((ext_vector_type(2)));

// ws layout (units: shorts): Q | K | V, 1M shorts each
#define QOFF  0u
#define KOFF  (1u << 20)
#define VOFF  (2u << 20)

static __device__ __forceinline__ unsigned short f2bf(float f) {
  union { float f; uint32_t u; } v; v.f = f;
  uint32_t r = (v.u + 0x7FFFu + ((v.u >> 16) & 1u)) >> 16;  // RNE
  return (unsigned short)r;
}
static __device__ __forceinline__ uint32_t pkrne(float lo, float hi) {
  return (uint32_t)f2bf(lo) | ((uint32_t)f2bf(hi) << 16);
}
static __device__ __forceinline__ uint32_t pktrunc(float lo, float hi) {
  return (__builtin_bit_cast(uint32_t, hi) & 0xffff0000u) |
         (__builtin_bit_cast(uint32_t, lo) >> 16);
}
static __device__ __forceinline__ float fexp2(float x) {
  float r;
  asm("v_exp_f32 %0, %1" : "=v"(r) : "v"(x));  // non-volatile: schedulable
  return r;
}
static __device__ __forceinline__ f32x16 zero16() {
  f32x16 z;
#pragma unroll
  for (int i = 0; i < 16; ++i) z[i] = 0.f;
  return z;
}
// swap bits 2,3 (V spatial permutation within each 32-block)
static __device__ __forceinline__ int perm23(int p) {
  return (p & ~12) | ((p & 4) << 1) | ((p & 8) >> 1);
}
static __device__ __forceinline__ bf16x8 pack8(float f0, float f1, float f2,
                                               float f3, float f4, float f5,
                                               float f6, float f7) {
  uint4 u = make_uint4(pkrne(f0, f1), pkrne(f2, f3), pkrne(f4, f5), pkrne(f6, f7));
  return __builtin_bit_cast(bf16x8, u);
}

// ---------------------------------------------------------------------------
// proj (MFMA, fused fp32->bf16): D[out 32][p 32], K=128.
// grid = b*48 + mat*16 + ptile (384), block = 256 (4 waves; wave = 32-out
// m-tile, 2 n-tiles of 32 p). Q/K stored [bn][p][d] (Q scaled by
// 0.25*log2e); V stored [bn][d][perm23(p)].  (identical to R9)
// ---------------------------------------------------------------------------
__global__ __launch_bounds__(256) void proj_kernel(
    const float* __restrict__ x, const float* __restrict__ wq,
    const float* __restrict__ wk, const float* __restrict__ wv,
    unsigned short* __restrict__ ws) {
  int bid = blockIdx.x;
  int ptile = bid & 15;
  int mat = (bid >> 4) % 3;
  int b = bid / 48;
  int t = threadIdx.x;
  int wave = t >> 6, lane = t & 63;
  int h = lane >> 5, c = lane & 31;
  int out0 = wave * 32;

  const float* w = (mat == 0) ? wq : ((mat == 1) ? wk : wv);
  const float* wrow = w + (size_t)(out0 + c) * 128 + h * 8;      // A: W[out0+c][k]
  const float* xcol = x + (size_t)b * 131072 + ptile * 64 + c;   // B: x[ch][p]

  f32x16 acc0 = zero16(), acc1 = zero16();
#pragma unroll
  for (int kt = 0; kt < 8; ++kt) {
    int ch0 = kt * 16 + h * 8;
    float4 wa = *(const float4*)(wrow + kt * 16);
    float4 wb4 = *(const float4*)(wrow + kt * 16 + 4);
    float xb0[8], xb1[8];
#pragma unroll
    for (int j = 0; j < 8; ++j) {
      xb0[j] = xcol[(size_t)(ch0 + j) * 1024];
      xb1[j] = xcol[(size_t)(ch0 + j) * 1024 + 32];
    }
    bf16x8 af = pack8(wa.x, wa.y, wa.z, wa.w, wb4.x, wb4.y, wb4.z, wb4.w);
    bf16x8 b0 = pack8(xb0[0], xb0[1], xb0[2], xb0[3], xb0[4], xb0[5], xb0[6], xb0[7]);
    bf16x8 b1 = pack8(xb1[0], xb1[1], xb1[2], xb1[3], xb1[4], xb1[5], xb1[6], xb1[7]);
    acc0 = __builtin_amdgcn_mfma_f32_32x32x16_bf16(af, b0, acc0, 0, 0, 0);
    acc1 = __builtin_amdgcn_mfma_f32_32x32x16_bf16(af, b1, acc1, 0, 0, 0);
  }

  if (mat < 2) {
    // Q: fold softmax scale d^-0.5 * log2(e) (attn uses exp2)
    float s = (mat == 0) ? 0.36067376022224085f : 1.0f;
    unsigned short* dst = ws + ((mat == 0) ? QOFF : KOFF);
#pragma unroll
    for (int nt = 0; nt < 2; ++nt) {
      f32x16 a = nt ? acc1 : acc0;
      int p = ptile * 64 + nt * 32 + c;
#pragma unroll
      for (int rg = 0; rg < 4; ++rg) {
        int bn = b * 8 + wave * 2 + (rg >> 1);
        int dbase = ((rg & 1) ? 8 : 0) + 4 * h;
        uint32_t lo = pkrne(a[rg * 4 + 0] * s, a[rg * 4 + 1] * s);
        uint32_t hi = pkrne(a[rg * 4 + 2] * s, a[rg * 4 + 3] * s);
        *(uint2*)(dst + (size_t)bn * 16384 + (size_t)p * 16 + dbase) =
            make_uint2(lo, hi);
      }
    }
  } else {
#pragma unroll
    for (int nt = 0; nt < 2; ++nt) {
      f32x16 a = nt ? acc1 : acc0;
      int p = ptile * 64 + nt * 32 + c;
      int pp = perm23(p);
#pragma unroll
      for (int r = 0; r < 16; ++r) {
        int moff = (r & 3) + 8 * (r >> 2) + 4 * h;
        int head = (out0 + moff) >> 4;
        int d = moff & 15;
        ws[VOFF + (size_t)(b * 8 + head) * 16384 + (size_t)d * 1024 + pp] =
            f2bf(a[r]);
      }
    }
  }
}

// ---------------------------------------------------------------------------
// attn: grid = bn*8+qc (512), block = 256 (4 waves), 32 q/wave, 32 x-blocks.
// No LDS, no barriers, direct stores. Per x-block:
//   sv = mfma32(K, Q^T)            (S^T, K=16 exact)
//   e  = exp2(sv)                  (16 in-lane, unnormalized)
//   pk = trunc-pack(e)             (no rs on this path!)
//   pv = mfma32(V',P0,0); pv = mfma32(V',P1,pv)   (per-x tile)
//   [parallel: sum tree + shfl + rcp -> rs]
//   acc[r] += rs * pv[r]           (8 fmacs; lane's D-regs share q=c)
// ---------------------------------------------------------------------------
__global__ __launch_bounds__(256) void attn_kernel(
    const unsigned short* __restrict__ ws, float* __restrict__ out) {
  int bid = blockIdx.x;
  int qc = bid & 7, bn = bid >> 3;
  const unsigned short* Qg = ws + QOFF + (size_t)bn * 16384;
  const unsigned short* Kg = ws + KOFF + (size_t)bn * 16384;
  const unsigned short* Vg = ws + VOFF + (size_t)bn * 16384;

  int t = threadIdx.x;
  int wave = t >> 6, lane = t & 63;
  int h = lane >> 5, c = lane & 31;
  int q0 = qc * 128 + wave * 32;

  // Q B-frag: B[k=d=8h+j][n=q=c], K=16 exact
  bf16x8 qb = __builtin_bit_cast(
      bf16x8, *(const uint4*)(Qg + (size_t)(q0 + c) * 16 + h * 8));

  // K A-frag: lane reads K[x*32 + c][8h..8h+7]  (coalesced 16B/lane)
  const unsigned short* kbase = Kg + (size_t)c * 16 + h * 8;
  // V A-frag: lane reads V'[c&15][x*32 + 8h..]
  const unsigned short* vbase = Vg + (size_t)(c & 15) * 1024 + h * 8;

  float acc[8];
#pragma unroll
  for (int r = 0; r < 8; ++r) acc[r] = 0.f;

  uint4 kf  = *(const uint4*)(kbase);
  uint4 v0f = *(const uint4*)(vbase);
  uint4 v1f = *(const uint4*)(vbase + 16);

#pragma unroll 2
  for (int x = 0; x < 32; ++x) {
    bf16x8 ka  = __builtin_bit_cast(bf16x8, kf);
    bf16x8 va0 = __builtin_bit_cast(bf16x8, v0f);
    bf16x8 va1 = __builtin_bit_cast(bf16x8, v1f);
    if (x < 31) {  // prefetch next x-block
      kf  = *(const uint4*)(kbase + (size_t)(x + 1) * 512);
      v0f = *(const uint4*)(vbase + (x + 1) * 32);
      v1f = *(const uint4*)(vbase + (x + 1) * 32 + 16);
    }

    // S^T[slot=(r&3)+8(r>>2)+4h][q=c], slot = natural y within block
    f32x16 sv = __builtin_amdgcn_mfma_f32_32x32x16_bf16(ka, qb, zero16(), 0, 0, 0);

    // 16 exp2 (independent, unnormalized; |score| <~ 9 -> e <= ~512, safe)
    float e[16];
#pragma unroll
    for (int r = 0; r < 16; ++r) e[r] = fexp2(sv[r]);

    // pack unnormalized scores for PV (critical path: exp -> pack -> mfma)
    uint32_t pk[8];
#pragma unroll
    for (int j = 0; j < 8; ++j) pk[j] = pktrunc(e[2 * j], e[2 * j + 1]);
    bf16x8 p0 = __builtin_bit_cast(bf16x8, make_uint4(pk[0], pk[1], pk[2], pk[3]));
    bf16x8 p1 = __builtin_bit_cast(bf16x8, make_uint4(pk[4], pk[5], pk[6], pk[7]));

    // per-x PV tile on unnormalized P (C=0)
    f32x16 pv = __builtin_amdgcn_mfma_f32_32x32x16_bf16(va0, p0, zero16(), 0, 0, 0);
    pv = __builtin_amdgcn_mfma_f32_32x32x16_bf16(va1, p1, pv, 0, 0, 0);

    // off-path reduction: sum tree + cross-half shfl + rcp
    float s0 = (e[0] + e[1]) + (e[2] + e[3]);
    float s1 = (e[4] + e[5]) + (e[6] + e[7]);
    float s2 = (e[8] + e[9]) + (e[10] + e[11]);
    float s3 = (e[12] + e[13]) + (e[14] + e[15]);
    float sum = (s0 + s1) + (s2 + s3);
    sum += __shfl_xor(sum, 32);
    float rs = __builtin_amdgcn_rcpf(sum);

    // fold normalization in after PV: lane's D-regs all have q=c
#pragma unroll
    for (int r = 0; r < 8; ++r) acc[r] = fmaf(rs, pv[r], acc[r]);
  }

  // Epilogue: D rows 0..15 valid (rows 16..31 are duplicate-V garbage)
#pragma unroll
  for (int r = 0; r < 8; ++r) {
    int d = (r & 3) + 8 * (r >> 2) + 4 * h;
    out[(size_t)(bn * 16 + d) * 1024 + q0 + c] = acc[r];
  }
}

// ---------------------------------------------------------------------------
extern "C" void kernel_launch(void* const* d_in, const int* in_sizes, int n_in,
                              void* d_out, int out_size, void* d_ws, size_t ws_size,
                              hipStream_t stream) {
  const float* x  = (const float*)d_in[0];
  const float* wq = (const float*)d_in[1];
  const float* wk = (const float*)d_in[2];
  const float* wv = (const float*)d_in[3];
  unsigned short* ws = (unsigned short*)d_ws;
  float* out = (float*)d_out;

  proj_kernel<<<dim3(384), dim3(256), 0, stream>>>(x, wq, wk, wv, ws);
  attn_kernel<<<dim3(512), dim3(256), 0, stream>>>(ws, out);
}

// Round 12
// 89.555 us; speedup vs baseline: 1.8541x; 1.0237x over previous
//
#include <hip/hip_runtime.h>
#include <stdint.h>

// MHABlock: b=8, c=128, heads=8, d=16, spatial 32x32 (p=1024).
// Softmax over last spatial axis only -> independent 32-key blocks.
// R12: software-pipelined attn. S-MFMA for iteration x+1 issues at the top of
// iteration x (distance-2 operand prefetch, clamped indices), so exp consumes
// an S-tile computed a full iteration earlier -> S-MFMA latency off the
// critical path. PV split into two independent C=0 tiles, combined in the
// off-path normalization fmacs. Deferred normalization as R11 (passed,
// 91.7us, absmax 0.125). S^T = K*Q^T via mfma_32x32x16 (K=16 exact); V
// stored y-bits-2,3-swapped so PV B-frags are sequential in-lane packs.

typedef __bf16 bf16x8 __attribute__((ext_vector_type(8)));
typedef float f32x16 __attribute__((ext_vector_type(16)));

// ws layout (units: shorts): Q | K | V, 1M shorts each
#define QOFF  0u
#define KOFF  (1u << 20)
#define VOFF  (2u << 20)

static __device__ __forceinline__ unsigned short f2bf(float f) {
  union { float f; uint32_t u; } v; v.f = f;
  uint32_t r = (v.u + 0x7FFFu + ((v.u >> 16) & 1u)) >> 16;  // RNE
  return (unsigned short)r;
}
static __device__ __forceinline__ uint32_t pkrne(float lo, float hi) {
  return (uint32_t)f2bf(lo) | ((uint32_t)f2bf(hi) << 16);
}
static __device__ __forceinline__ uint32_t pktrunc(float lo, float hi) {
  return (__builtin_bit_cast(uint32_t, hi) & 0xffff0000u) |
         (__builtin_bit_cast(uint32_t, lo) >> 16);
}
static __device__ __forceinline__ float fexp2(float x) {
  float r;
  asm("v_exp_f32 %0, %1" : "=v"(r) : "v"(x));  // non-volatile: schedulable
  return r;
}
static __device__ __forceinline__ f32x16 zero16() {
  f32x16 z;
#pragma unroll
  for (int i = 0; i < 16; ++i) z[i] = 0.f;
  return z;
}
// swap bits 2,3 (V spatial permutation within each 32-block)
static __device__ __forceinline__ int perm23(int p) {
  return (p & ~12) | ((p & 4) << 1) | ((p & 8) >> 1);
}
static __device__ __forceinline__ bf16x8 pack8(float f0, float f1, float f2,
                                               float f3, float f4, float f5,
                                               float f6, float f7) {
  uint4 u = make_uint4(pkrne(f0, f1), pkrne(f2, f3), pkrne(f4, f5), pkrne(f6, f7));
  return __builtin_bit_cast(bf16x8, u);
}

// ---------------------------------------------------------------------------
// proj (MFMA, fused fp32->bf16): D[out 32][p 32], K=128.
// grid = b*48 + mat*16 + ptile (384), block = 256.  (identical to R9/R11)
// ---------------------------------------------------------------------------
__global__ __launch_bounds__(256) void proj_kernel(
    const float* __restrict__ x, const float* __restrict__ wq,
    const float* __restrict__ wk, const float* __restrict__ wv,
    unsigned short* __restrict__ ws) {
  int bid = blockIdx.x;
  int ptile = bid & 15;
  int mat = (bid >> 4) % 3;
  int b = bid / 48;
  int t = threadIdx.x;
  int wave = t >> 6, lane = t & 63;
  int h = lane >> 5, c = lane & 31;
  int out0 = wave * 32;

  const float* w = (mat == 0) ? wq : ((mat == 1) ? wk : wv);
  const float* wrow = w + (size_t)(out0 + c) * 128 + h * 8;      // A: W[out0+c][k]
  const float* xcol = x + (size_t)b * 131072 + ptile * 64 + c;   // B: x[ch][p]

  f32x16 acc0 = zero16(), acc1 = zero16();
#pragma unroll
  for (int kt = 0; kt < 8; ++kt) {
    int ch0 = kt * 16 + h * 8;
    float4 wa = *(const float4*)(wrow + kt * 16);
    float4 wb4 = *(const float4*)(wrow + kt * 16 + 4);
    float xb0[8], xb1[8];
#pragma unroll
    for (int j = 0; j < 8; ++j) {
      xb0[j] = xcol[(size_t)(ch0 + j) * 1024];
      xb1[j] = xcol[(size_t)(ch0 + j) * 1024 + 32];
    }
    bf16x8 af = pack8(wa.x, wa.y, wa.z, wa.w, wb4.x, wb4.y, wb4.z, wb4.w);
    bf16x8 b0 = pack8(xb0[0], xb0[1], xb0[2], xb0[3], xb0[4], xb0[5], xb0[6], xb0[7]);
    bf16x8 b1 = pack8(xb1[0], xb1[1], xb1[2], xb1[3], xb1[4], xb1[5], xb1[6], xb1[7]);
    acc0 = __builtin_amdgcn_mfma_f32_32x32x16_bf16(af, b0, acc0, 0, 0, 0);
    acc1 = __builtin_amdgcn_mfma_f32_32x32x16_bf16(af, b1, acc1, 0, 0, 0);
  }

  if (mat < 2) {
    // Q: fold softmax scale d^-0.5 * log2(e) (attn uses exp2)
    float s = (mat == 0) ? 0.36067376022224085f : 1.0f;
    unsigned short* dst = ws + ((mat == 0) ? QOFF : KOFF);
#pragma unroll
    for (int nt = 0; nt < 2; ++nt) {
      f32x16 a = nt ? acc1 : acc0;
      int p = ptile * 64 + nt * 32 + c;
#pragma unroll
      for (int rg = 0; rg < 4; ++rg) {
        int bn = b * 8 + wave * 2 + (rg >> 1);
        int dbase = ((rg & 1) ? 8 : 0) + 4 * h;
        uint32_t lo = pkrne(a[rg * 4 + 0] * s, a[rg * 4 + 1] * s);
        uint32_t hi = pkrne(a[rg * 4 + 2] * s, a[rg * 4 + 3] * s);
        *(uint2*)(dst + (size_t)bn * 16384 + (size_t)p * 16 + dbase) =
            make_uint2(lo, hi);
      }
    }
  } else {
#pragma unroll
    for (int nt = 0; nt < 2; ++nt) {
      f32x16 a = nt ? acc1 : acc0;
      int p = ptile * 64 + nt * 32 + c;
      int pp = perm23(p);
#pragma unroll
      for (int r = 0; r < 16; ++r) {
        int moff = (r & 3) + 8 * (r >> 2) + 4 * h;
        int head = (out0 + moff) >> 4;
        int d = moff & 15;
        ws[VOFF + (size_t)(b * 8 + head) * 16384 + (size_t)d * 1024 + pp] =
            f2bf(a[r]);
      }
    }
  }
}

// ---------------------------------------------------------------------------
// attn: grid = bn*8+qc (512), block = 256 (4 waves), 32 q/wave, 32 x-blocks.
// No LDS, no barriers, direct stores. Software pipeline: sv computed one
// iteration ahead; operand prefetch two iterations ahead (clamped).
// ---------------------------------------------------------------------------
__global__ __launch_bounds__(256) void attn_kernel(
    const unsigned short* __restrict__ ws, float* __restrict__ out) {
  int bid = blockIdx.x;
  int qc = bid & 7, bn = bid >> 3;
  const unsigned short* Qg = ws + QOFF + (size_t)bn * 16384;
  const unsigned short* Kg = ws + KOFF + (size_t)bn * 16384;
  const unsigned short* Vg = ws + VOFF + (size_t)bn * 16384;

  int t = threadIdx.x;
  int wave = t >> 6, lane = t & 63;
  int h = lane >> 5, c = lane & 31;
  int q0 = qc * 128 + wave * 32;

  // Q B-frag: B[k=d=8h+j][n=q=c], K=16 exact
  bf16x8 qb = __builtin_bit_cast(
      bf16x8, *(const uint4*)(Qg + (size_t)(q0 + c) * 16 + h * 8));

  // K A-frag: lane reads K[x*32 + c][8h..8h+7]  (coalesced 16B/lane)
  const unsigned short* kbase = Kg + (size_t)c * 16 + h * 8;
  // V A-frag: lane reads V'[c&15][x*32 + 8h..]
  const unsigned short* vbase = Vg + (size_t)(c & 15) * 1024 + h * 8;

  float acc[8];
#pragma unroll
  for (int r = 0; r < 8; ++r) acc[r] = 0.f;

  // pipeline prologue: operands for x=0, sv for x=0, operands for x=1
  uint4 v0_a = *(const uint4*)(vbase);
  uint4 v1_a = *(const uint4*)(vbase + 16);
  uint4 kf_b = *(const uint4*)(kbase + 512);       // K(1)
  uint4 v0_b = *(const uint4*)(vbase + 32);        // V0(1)
  uint4 v1_b = *(const uint4*)(vbase + 48);        // V1(1)
  f32x16 sv;
  {
    uint4 kf0 = *(const uint4*)(kbase);
    sv = __builtin_amdgcn_mfma_f32_32x32x16_bf16(
        __builtin_bit_cast(bf16x8, kf0), qb, zero16(), 0, 0, 0);
  }

#pragma unroll 2
  for (int x = 0; x < 32; ++x) {
    // current V operands (for this x)
    bf16x8 va0 = __builtin_bit_cast(bf16x8, v0_a);
    bf16x8 va1 = __builtin_bit_cast(bf16x8, v1_a);

    // issue sv for x+1 NOW (operands prefetched last iteration); the exps
    // below consume the sv computed in the PREVIOUS iteration.
    f32x16 sv_next = __builtin_amdgcn_mfma_f32_32x32x16_bf16(
        __builtin_bit_cast(bf16x8, kf_b), qb, zero16(), 0, 0, 0);

    // rotate prefetch regs; fetch x+2 (clamped -> branch-free, redundant at end)
    v0_a = v0_b; v1_a = v1_b;
    int x2 = (x > 29) ? 31 : (x + 2);
    kf_b = *(const uint4*)(kbase + (size_t)x2 * 512);
    v0_b = *(const uint4*)(vbase + x2 * 32);
    v1_b = *(const uint4*)(vbase + x2 * 32 + 16);

    // S^T[slot=(r&3)+8(r>>2)+4h][q=c] -> 16 exp2 (unnormalized)
    float e[16];
#pragma unroll
    for (int r = 0; r < 16; ++r) e[r] = fexp2(sv[r]);

    // pack unnormalized scores (critical path: exp -> pack -> PV)
    uint32_t pk[8];
#pragma unroll
    for (int j = 0; j < 8; ++j) pk[j] = pktrunc(e[2 * j], e[2 * j + 1]);
    bf16x8 p0 = __builtin_bit_cast(bf16x8, make_uint4(pk[0], pk[1], pk[2], pk[3]));
    bf16x8 p1 = __builtin_bit_cast(bf16x8, make_uint4(pk[4], pk[5], pk[6], pk[7]));

    // two INDEPENDENT per-x PV tiles (C=0 each; no serial C dependency)
    f32x16 pv0 = __builtin_amdgcn_mfma_f32_32x32x16_bf16(va0, p0, zero16(), 0, 0, 0);
    f32x16 pv1 = __builtin_amdgcn_mfma_f32_32x32x16_bf16(va1, p1, zero16(), 0, 0, 0);

    // off-path reduction: sum tree + cross-half shfl + rcp
    float s0 = (e[0] + e[1]) + (e[2] + e[3]);
    float s1 = (e[4] + e[5]) + (e[6] + e[7]);
    float s2 = (e[8] + e[9]) + (e[10] + e[11]);
    float s3 = (e[12] + e[13]) + (e[14] + e[15]);
    float sum = (s0 + s1) + (s2 + s3);
    sum += __shfl_xor(sum, 32);
    float rs = __builtin_amdgcn_rcpf(sum);

    // fold normalization after PV: lane's D-regs all share q=c
#pragma unroll
    for (int r = 0; r < 8; ++r) acc[r] = fmaf(rs, pv0[r] + pv1[r], acc[r]);

    sv = sv_next;  // rotate pipeline
  }

  // Epilogue: D rows 0..15 valid (rows 16..31 are duplicate-V garbage)
#pragma unroll
  for (int r = 0; r < 8; ++r) {
    int d = (r & 3) + 8 * (r >> 2) + 4 * h;
    out[(size_t)(bn * 16 + d) * 1024 + q0 + c] = acc[r];
  }
}

// ---------------------------------------------------------------------------
extern "C" void kernel_launch(void* const* d_in, const int* in_sizes, int n_in,
                              void* d_out, int out_size, void* d_ws, size_t ws_size,
                              hipStream_t stream) {
  const float* x  = (const float*)d_in[0];
  const float* wq = (const float*)d_in[1];
  const float* wk = (const float*)d_in[2];
  const float* wv = (const float*)d_in[3];
  unsigned short* ws = (unsigned short*)d_ws;
  float* out = (float*)d_out;

  proj_kernel<<<dim3(384), dim3(256), 0, stream>>>(x, wq, wk, wv, ws);
  attn_kernel<<<dim3(512), dim3(256), 0, stream>>>(ws, out);
}

// Round 13
// 88.359 us; speedup vs baseline: 1.8792x; 1.0135x over previous
//
#include <hip/hip_runtime.h>
#include <stdint.h>

// MHABlock: b=8, c=128, heads=8, d=16, spatial 32x32 (p=1024).
// Softmax over last spatial axis only -> independent 32-key blocks.
// R13: 3-stage software-pipelined attn. Iter x: (1) issue S-MFMA for x+1;
// (2) exp/sum/rcp for x (sv from iter x-1); (3) pack+PV+rs-fold for x-1
// (e/rs from iter x-1, V held from x-1). No stage consumes a same-iteration
// value -> exp and S-MFMA latency both off the critical path.
// Deferred normalization (R11), distance-2 operand prefetch (R12).
// S^T = K*Q^T via mfma_32x32x16 (K=16 exact); V stored y-bits-2,3-swapped so
// PV B-frags are sequential in-lane packs of the exp'd scores.

typedef __bf16 bf16x8 __attribute__((ext_vector_type(8)));
typedef float f32x16 __attribute__((ext_vector_type(16)));

// ws layout (units: shorts): Q | K | V, 1M shorts each
#define QOFF  0u
#define KOFF  (1u << 20)
#define VOFF  (2u << 20)

static __device__ __forceinline__ unsigned short f2bf(float f) {
  union { float f; uint32_t u; } v; v.f = f;
  uint32_t r = (v.u + 0x7FFFu + ((v.u >> 16) & 1u)) >> 16;  // RNE
  return (unsigned short)r;
}
static __device__ __forceinline__ uint32_t pkrne(float lo, float hi) {
  return (uint32_t)f2bf(lo) | ((uint32_t)f2bf(hi) << 16);
}
static __device__ __forceinline__ uint32_t pktrunc(float lo, float hi) {
  return (__builtin_bit_cast(uint32_t, hi) & 0xffff0000u) |
         (__builtin_bit_cast(uint32_t, lo) >> 16);
}
static __device__ __forceinline__ float fexp2(float x) {
  float r;
  asm("v_exp_f32 %0, %1" : "=v"(r) : "v"(x));  // non-volatile: schedulable
  return r;
}
static __device__ __forceinline__ f32x16 zero16() {
  f32x16 z;
#pragma unroll
  for (int i = 0; i < 16; ++i) z[i] = 0.f;
  return z;
}
// swap bits 2,3 (V spatial permutation within each 32-block)
static __device__ __forceinline__ int perm23(int p) {
  return (p & ~12) | ((p & 4) << 1) | ((p & 8) >> 1);
}
static __device__ __forceinline__ bf16x8 pack8(float f0, float f1, float f2,
                                               float f3, float f4, float f5,
                                               float f6, float f7) {
  uint4 u = make_uint4(pkrne(f0, f1), pkrne(f2, f3), pkrne(f4, f5), pkrne(f6, f7));
  return __builtin_bit_cast(bf16x8, u);
}

// ---------------------------------------------------------------------------
// proj (MFMA, fused fp32->bf16): D[out 32][p 32], K=128.
// grid = b*48 + mat*16 + ptile (384), block = 256.  (identical to R9..R12)
// ---------------------------------------------------------------------------
__global__ __launch_bounds__(256) void proj_kernel(
    const float* __restrict__ x, const float* __restrict__ wq,
    const float* __restrict__ wk, const float* __restrict__ wv,
    unsigned short* __restrict__ ws) {
  int bid = blockIdx.x;
  int ptile = bid & 15;
  int mat = (bid >> 4) % 3;
  int b = bid / 48;
  int t = threadIdx.x;
  int wave = t >> 6, lane = t & 63;
  int h = lane >> 5, c = lane & 31;
  int out0 = wave * 32;

  const float* w = (mat == 0) ? wq : ((mat == 1) ? wk : wv);
  const float* wrow = w + (size_t)(out0 + c) * 128 + h * 8;      // A: W[out0+c][k]
  const float* xcol = x + (size_t)b * 131072 + ptile * 64 + c;   // B: x[ch][p]

  f32x16 acc0 = zero16(), acc1 = zero16();
#pragma unroll
  for (int kt = 0; kt < 8; ++kt) {
    int ch0 = kt * 16 + h * 8;
    float4 wa = *(const float4*)(wrow + kt * 16);
    float4 wb4 = *(const float4*)(wrow + kt * 16 + 4);
    float xb0[8], xb1[8];
#pragma unroll
    for (int j = 0; j < 8; ++j) {
      xb0[j] = xcol[(size_t)(ch0 + j) * 1024];
      xb1[j] = xcol[(size_t)(ch0 + j) * 1024 + 32];
    }
    bf16x8 af = pack8(wa.x, wa.y, wa.z, wa.w, wb4.x, wb4.y, wb4.z, wb4.w);
    bf16x8 b0 = pack8(xb0[0], xb0[1], xb0[2], xb0[3], xb0[4], xb0[5], xb0[6], xb0[7]);
    bf16x8 b1 = pack8(xb1[0], xb1[1], xb1[2], xb1[3], xb1[4], xb1[5], xb1[6], xb1[7]);
    acc0 = __builtin_amdgcn_mfma_f32_32x32x16_bf16(af, b0, acc0, 0, 0, 0);
    acc1 = __builtin_amdgcn_mfma_f32_32x32x16_bf16(af, b1, acc1, 0, 0, 0);
  }

  if (mat < 2) {
    // Q: fold softmax scale d^-0.5 * log2(e) (attn uses exp2)
    float s = (mat == 0) ? 0.36067376022224085f : 1.0f;
    unsigned short* dst = ws + ((mat == 0) ? QOFF : KOFF);
#pragma unroll
    for (int nt = 0; nt < 2; ++nt) {
      f32x16 a = nt ? acc1 : acc0;
      int p = ptile * 64 + nt * 32 + c;
#pragma unroll
      for (int rg = 0; rg < 4; ++rg) {
        int bn = b * 8 + wave * 2 + (rg >> 1);
        int dbase = ((rg & 1) ? 8 : 0) + 4 * h;
        uint32_t lo = pkrne(a[rg * 4 + 0] * s, a[rg * 4 + 1] * s);
        uint32_t hi = pkrne(a[rg * 4 + 2] * s, a[rg * 4 + 3] * s);
        *(uint2*)(dst + (size_t)bn * 16384 + (size_t)p * 16 + dbase) =
            make_uint2(lo, hi);
      }
    }
  } else {
#pragma unroll
    for (int nt = 0; nt < 2; ++nt) {
      f32x16 a = nt ? acc1 : acc0;
      int p = ptile * 64 + nt * 32 + c;
      int pp = perm23(p);
#pragma unroll
      for (int r = 0; r < 16; ++r) {
        int moff = (r & 3) + 8 * (r >> 2) + 4 * h;
        int head = (out0 + moff) >> 4;
        int d = moff & 15;
        ws[VOFF + (size_t)(b * 8 + head) * 16384 + (size_t)d * 1024 + pp] =
            f2bf(a[r]);
      }
    }
  }
}

// ---------------------------------------------------------------------------
// attn: grid = bn*8+qc (512), block = 256 (4 waves), 32 q/wave, 32 x-blocks.
// No LDS, no barriers, direct stores. 3-stage pipeline (see header).
// ---------------------------------------------------------------------------
__global__ __launch_bounds__(256) void attn_kernel(
    const unsigned short* __restrict__ ws, float* __restrict__ out) {
  int bid = blockIdx.x;
  int qc = bid & 7, bn = bid >> 3;
  const unsigned short* Qg = ws + QOFF + (size_t)bn * 16384;
  const unsigned short* Kg = ws + KOFF + (size_t)bn * 16384;
  const unsigned short* Vg = ws + VOFF + (size_t)bn * 16384;

  int t = threadIdx.x;
  int wave = t >> 6, lane = t & 63;
  int h = lane >> 5, c = lane & 31;
  int q0 = qc * 128 + wave * 32;

  // Q B-frag: B[k=d=8h+j][n=q=c], K=16 exact
  bf16x8 qb = __builtin_bit_cast(
      bf16x8, *(const uint4*)(Qg + (size_t)(q0 + c) * 16 + h * 8));

  // K A-frag: lane reads K[x*32 + c][8h..8h+7]  (coalesced 16B/lane)
  const unsigned short* kbase = Kg + (size_t)c * 16 + h * 8;
  // V A-frag: lane reads V'[c&15][x*32 + 8h..]
  const unsigned short* vbase = Vg + (size_t)(c & 15) * 1024 + h * 8;

  float acc[8];
#pragma unroll
  for (int r = 0; r < 8; ++r) acc[r] = 0.f;

  // ---- prologue ----
  // V slots: va_p = frags for x-1 ; v_c = raw V(x) ; v_n = raw V(x+1)
  bf16x8 va0_p = __builtin_bit_cast(bf16x8, *(const uint4*)(vbase));
  bf16x8 va1_p = __builtin_bit_cast(bf16x8, *(const uint4*)(vbase + 16));
  uint4 v0_c = *(const uint4*)(vbase + 32);        // V(1)
  uint4 v1_c = *(const uint4*)(vbase + 48);
  uint4 v0_n = *(const uint4*)(vbase + 64);        // V(2)
  uint4 v1_n = *(const uint4*)(vbase + 80);

  // S(0) -> stage2(0) now (prologue)
  f32x16 sv_cur;
  {
    uint4 kf0 = *(const uint4*)(kbase);
    f32x16 sv0 = __builtin_amdgcn_mfma_f32_32x32x16_bf16(
        __builtin_bit_cast(bf16x8, kf0), qb, zero16(), 0, 0, 0);
    uint4 kf1 = *(const uint4*)(kbase + 512);
    sv_cur = __builtin_amdgcn_mfma_f32_32x32x16_bf16(   // S(1)
        __builtin_bit_cast(bf16x8, kf1), qb, zero16(), 0, 0, 0);
    // fall through to stage2(0) below using sv0
    float e0[16];
#pragma unroll
    for (int r = 0; r < 16; ++r) e0[r] = fexp2(sv0[r]);
    float s0 = (e0[0] + e0[1]) + (e0[2] + e0[3]);
    float s1 = (e0[4] + e0[5]) + (e0[6] + e0[7]);
    float s2 = (e0[8] + e0[9]) + (e0[10] + e0[11]);
    float s3 = (e0[12] + e0[13]) + (e0[14] + e0[15]);
    float sum = (s0 + s1) + (s2 + s3);
    sum += __shfl_xor(sum, 32);
    float rs0 = __builtin_amdgcn_rcpf(sum);
    // seed e_prev/rs_prev with x=0 values
    float e_prev[16];
#pragma unroll
    for (int r = 0; r < 16; ++r) e_prev[r] = e0[r];
    float rs_prev = rs0;

    uint4 kf_a = *(const uint4*)(kbase + 2 * 512);   // K(2)
    uint4 kf_b = *(const uint4*)(kbase + 3 * 512);   // K(3)

    // ---- main loop: x = 1..31 ----
#pragma unroll 2
    for (int x = 1; x < 32; ++x) {
      // stage1: issue S(x+1) (kf_a = K(x+1)); redundant clamp at x=31
      f32x16 sv_next = __builtin_amdgcn_mfma_f32_32x32x16_bf16(
          __builtin_bit_cast(bf16x8, kf_a), qb, zero16(), 0, 0, 0);
      kf_a = kf_b;
      int x3 = (x > 28) ? 31 : (x + 3);
      kf_b = *(const uint4*)(kbase + (size_t)x3 * 512);

      // stage3 for x-1: pack e_prev -> PV (two independent C=0 tiles) -> fold
      uint32_t pk[8];
#pragma unroll
      for (int j = 0; j < 8; ++j) pk[j] = pktrunc(e_prev[2 * j], e_prev[2 * j + 1]);
      bf16x8 p0 = __builtin_bit_cast(bf16x8, make_uint4(pk[0], pk[1], pk[2], pk[3]));
      bf16x8 p1 = __builtin_bit_cast(bf16x8, make_uint4(pk[4], pk[5], pk[6], pk[7]));
      f32x16 pv0 = __builtin_amdgcn_mfma_f32_32x32x16_bf16(va0_p, p0, zero16(), 0, 0, 0);
      f32x16 pv1 = __builtin_amdgcn_mfma_f32_32x32x16_bf16(va1_p, p1, zero16(), 0, 0, 0);
#pragma unroll
      for (int r = 0; r < 8; ++r) acc[r] = fmaf(rs_prev, pv0[r] + pv1[r], acc[r]);

      // stage2 for x: exp/sum/rcp on sv_cur (computed at iter x-1)
      float e_cur[16];
#pragma unroll
      for (int r = 0; r < 16; ++r) e_cur[r] = fexp2(sv_cur[r]);
      float t0 = (e_cur[0] + e_cur[1]) + (e_cur[2] + e_cur[3]);
      float t1 = (e_cur[4] + e_cur[5]) + (e_cur[6] + e_cur[7]);
      float t2 = (e_cur[8] + e_cur[9]) + (e_cur[10] + e_cur[11]);
      float t3 = (e_cur[12] + e_cur[13]) + (e_cur[14] + e_cur[15]);
      float su = (t0 + t1) + (t2 + t3);
      su += __shfl_xor(su, 32);
      float rs_cur = __builtin_amdgcn_rcpf(su);

      // rotate V: va_p <- V(x); v_c <- V(x+1); load V(x+2) into v_n
      va0_p = __builtin_bit_cast(bf16x8, v0_c);
      va1_p = __builtin_bit_cast(bf16x8, v1_c);
      v0_c = v0_n; v1_c = v1_n;
      int x2 = (x > 29) ? 31 : (x + 2);
      v0_n = *(const uint4*)(vbase + x2 * 32);
      v1_n = *(const uint4*)(vbase + x2 * 32 + 16);

      // rotate pipeline state
      sv_cur = sv_next;
#pragma unroll
      for (int r = 0; r < 16; ++r) e_prev[r] = e_cur[r];
      rs_prev = rs_cur;
    }

    // ---- epilogue: stage3 for x=31 ----
    uint32_t pk[8];
#pragma unroll
    for (int j = 0; j < 8; ++j) pk[j] = pktrunc(e_prev[2 * j], e_prev[2 * j + 1]);
    bf16x8 p0 = __builtin_bit_cast(bf16x8, make_uint4(pk[0], pk[1], pk[2], pk[3]));
    bf16x8 p1 = __builtin_bit_cast(bf16x8, make_uint4(pk[4], pk[5], pk[6], pk[7]));
    f32x16 pv0 = __builtin_amdgcn_mfma_f32_32x32x16_bf16(va0_p, p0, zero16(), 0, 0, 0);
    f32x16 pv1 = __builtin_amdgcn_mfma_f32_32x32x16_bf16(va1_p, p1, zero16(), 0, 0, 0);
#pragma unroll
    for (int r = 0; r < 8; ++r) acc[r] = fmaf(rs_prev, pv0[r] + pv1[r], acc[r]);
  }

  // Epilogue: D rows 0..15 valid (rows 16..31 are duplicate-V garbage)
#pragma unroll
  for (int r = 0; r < 8; ++r) {
    int d = (r & 3) + 8 * (r >> 2) + 4 * h;
    out[(size_t)(bn * 16 + d) * 1024 + q0 + c] = acc[r];
  }
}

// ---------------------------------------------------------------------------
extern "C" void kernel_launch(void* const* d_in, const int* in_sizes, int n_in,
                              void* d_out, int out_size, void* d_ws, size_t ws_size,
                              hipStream_t stream) {
  const float* x  = (const float*)d_in[0];
  const float* wq = (const float*)d_in[1];
  const float* wk = (const float*)d_in[2];
  const float* wv = (const float*)d_in[3];
  unsigned short* ws = (unsigned short*)d_ws;
  float* out = (float*)d_out;

  proj_kernel<<<dim3(384), dim3(256), 0, stream>>>(x, wq, wk, wv, ws);
  attn_kernel<<<dim3(512), dim3(256), 0, stream>>>(ws, out);
}